// Round 1
// baseline (451.062 us; speedup 1.0000x reference)
//
#include <hip/hip_runtime.h>
#include <hip/hip_bf16.h>

#define T_TOK 2048
#define H_DIM 1024
#define I_DIM 512
#define E_NUM 64
#define TOPK  6
#define NROWS (T_TOK * TOPK)

typedef __attribute__((ext_vector_type(8))) short bf16x8;
typedef __attribute__((ext_vector_type(4))) float f32x4;

union U4B8 { uint4 u; bf16x8 b; };
union F4U4 { f32x4 f; uint4 u; };

__device__ __forceinline__ unsigned int f2bf(float x) {
  unsigned int u = __float_as_uint(x);
  return (u + 0x7fffu + ((u >> 16) & 1u)) >> 16;   // RNE
}
__device__ __forceinline__ unsigned int pack2bf(float lo, float hi) {
  __hip_bfloat162 h = __float22bfloat162_rn(make_float2(lo, hi));
  return *reinterpret_cast<unsigned int*>(&h);     // v_cvt_pk_bf16_f32
}

// volatile asm load: compiler cannot sink it to the use site -> true prefetch
#define LOADF4(dst, p) \
  asm volatile("global_load_dwordx4 %0, %1, off" : "=v"(dst) : "v"(p))

#define WAITV0() do { asm volatile("s_waitcnt vmcnt(0)" ::: "memory"); \
  __builtin_amdgcn_sched_barrier(0); } while (0)

// producer barrier: drain LDS writes only; vmem loads stay in flight
#define BAR_LGKM() do { __builtin_amdgcn_sched_barrier(0); \
  asm volatile("s_waitcnt lgkmcnt(0)\n\ts_barrier" ::: "memory"); \
  __builtin_amdgcn_sched_barrier(0); } while (0)

// consumer barrier: no waitcnt at all
#define BAR_FREE() do { __builtin_amdgcn_sched_barrier(0); \
  asm volatile("s_barrier" ::: "memory"); \
  __builtin_amdgcn_sched_barrier(0); } while (0)

__device__ __forceinline__ void gload_lds16(const void* gsrc, void* ldst) {
  __builtin_amdgcn_global_load_lds(
      (const __attribute__((address_space(1))) unsigned int*)gsrc,
      (__attribute__((address_space(3))) unsigned int*)ldst, 16, 0, 0);
}

// ---------------- router: logits + sigmoid + grouped top-k + hs->bf16 ------
__global__ __launch_bounds__(64)
void router_kernel(const float* __restrict__ hs, const float* __restrict__ gw,
                   const float* __restrict__ eb, int* __restrict__ tk_id,
                   float* __restrict__ tk_w, unsigned short* __restrict__ xb)
{
  const int t = blockIdx.x;
  const int lane = threadIdx.x;          // lane == expert
  __shared__ float sh[H_DIM];
  const float4* hrow = (const float4*)(hs + (size_t)t * H_DIM);
  float4* sh4 = (float4*)sh;
  for (int i = lane; i < H_DIM / 4; i += 64) sh4[i] = hrow[i];
  __syncthreads();

  // emit bf16 copy of this token's row (consumed by gemm1 A-staging)
  {
    uint4* xrow = (uint4*)(xb + (size_t)t * H_DIM);
    #pragma unroll
    for (int f = 0; f < 2; ++f) {
      int i = lane + f * 64;                    // uint4 index 0..127
      float4 a = sh4[i * 2], b = sh4[i * 2 + 1];
      uint4 o;
      o.x = pack2bf(a.x, a.y); o.y = pack2bf(a.z, a.w);
      o.z = pack2bf(b.x, b.y); o.w = pack2bf(b.z, b.w);
      xrow[i] = o;
    }
  }

  const float* w = gw + (size_t)lane * H_DIM;
  float acc = 0.f;
  for (int k = 0; k < H_DIM; k += 4) {
    float4 wv = *(const float4*)(w + k);
    acc += sh[k] * wv.x + sh[k + 1] * wv.y + sh[k + 2] * wv.z + sh[k + 3] * wv.w;
  }
  const float score = 1.f / (1.f + expf(-acc));
  const float sfc = score + eb[lane];

  float m1v = sfc; int m1i = lane;
  #pragma unroll
  for (int d = 1; d < 8; d <<= 1) {
    float ov = __shfl_xor(m1v, d); int oi = __shfl_xor(m1i, d);
    if (ov > m1v || (ov == m1v && oi < m1i)) { m1v = ov; m1i = oi; }
  }
  float v2 = (lane == m1i) ? -INFINITY : sfc;
  #pragma unroll
  for (int d = 1; d < 8; d <<= 1) v2 = fmaxf(v2, __shfl_xor(v2, d));
  const float gscore = m1v + v2;

  const int myg = lane >> 3;
  int rank = 0;
  #pragma unroll
  for (int g = 0; g < 8; ++g) {
    float gs = __shfl(gscore, g * 8);
    if (gs > gscore || (gs == gscore && g < myg)) rank++;
  }
  float mv = (rank < 4) ? sfc : -INFINITY;

  int isel[TOPK]; float wsel[TOPK]; float wsum = 0.f;
  #pragma unroll
  for (int j = 0; j < TOPK; ++j) {
    float av = mv; int ai = lane;
    #pragma unroll
    for (int d = 1; d < 64; d <<= 1) {
      float ov = __shfl_xor(av, d); int oi = __shfl_xor(ai, d);
      if (ov > av || (ov == av && oi < ai)) { av = ov; ai = oi; }
    }
    float wj = __shfl(score, ai);
    isel[j] = ai; wsel[j] = wj; wsum += wj;
    if (lane == ai) mv = -INFINITY;
  }
  if (lane == 0) {
    float inv = 1.f / wsum;
    #pragma unroll
    for (int j = 0; j < TOPK; ++j) {
      tk_id[t * TOPK + j] = isel[j];
      tk_w[t * TOPK + j] = wsel[j] * inv;
    }
  }
}

// ---------------- counting-sort rows by expert ----------------
__global__ __launch_bounds__(1024)
void build_rows_kernel(const int* __restrict__ tk_id, const float* __restrict__ tk_w,
                       int* __restrict__ off, int* __restrict__ row_tok,
                       float* __restrict__ row_wt)
{
  __shared__ int cnt[E_NUM];
  __shared__ int base[E_NUM];
  const int tid = threadIdx.x;
  if (tid < E_NUM) cnt[tid] = 0;
  __syncthreads();
  for (int i = tid; i < NROWS; i += 1024) atomicAdd(&cnt[tk_id[i]], 1);
  __syncthreads();
  if (tid == 0) {
    int s = 0;
    for (int e = 0; e < E_NUM; ++e) { base[e] = s; off[e] = s; s += cnt[e]; }
    off[E_NUM] = s;
  }
  __syncthreads();
  if (tid < E_NUM) cnt[tid] = base[tid];
  __syncthreads();
  for (int i = tid; i < NROWS; i += 1024) {
    int e = tk_id[i];
    int p = atomicAdd(&cnt[e], 1);
    row_tok[p] = i / TOPK;
    row_wt[p] = tk_w[i];
  }
}

// ---------------- gemm1: act = silu(X@w1) * (X@w3) * wt  (bf16 out) --------
// BM=256 BN=64 BK=64, 4 waves (wave = 64 rows x 64 cols).
// Weights stream EXACTLY ONCE per expert (one row-tile covers R<=256).
// A staged from pre-converted bf16 hs (xb); B reg-prefetch fp32 -> pack bf16.
__global__ __launch_bounds__(256, 2)
void gemm1_kernel(const unsigned short* __restrict__ xb, const float* __restrict__ w1,
                  const float* __restrict__ w3, const int* __restrict__ off,
                  const int* __restrict__ row_tok, const float* __restrict__ row_wt,
                  unsigned short* __restrict__ act)
{
  const int e = blockIdx.z;
  const int r0 = off[e];
  const int R = off[e + 1] - r0;
  const int rt = blockIdx.y;
  if (rt * 256 >= R) return;
  const int n0 = blockIdx.x * 64;

  __shared__ unsigned int sA[256 * 8 * 4];   // 32KB bf16 [m][8x16B slots], slot^=(m&7)
  __shared__ unsigned int sB1[8 * 64 * 4];   // 8KB [c=k>>3][n][k-pair], swizzled
  __shared__ unsigned int sB3[8 * 64 * 4];
  __shared__ int s_tok[256];
  __shared__ float s_wt[256];

  const int tid = threadIdx.x;
  {
    int r = rt * 256 + tid;
    int rr = (r < R) ? r : (R - 1);
    s_tok[tid] = row_tok[r0 + rr];
    s_wt[tid] = (r < R) ? row_wt[r0 + r] : 0.f;
  }
  __syncthreads();

  const int lane = tid & 63;
  const int wv = tid >> 6;                   // wave = 64-row block
  const int l15 = lane & 15, lhi = lane >> 4;

  // A staging: thread tid stages row m=tid, 8 x uint4 (bf16) per K-step
  const char* xrow = (const char*)(xb + (size_t)s_tok[tid] * H_DIM);

  // B staging map: rows k0..k0+3, cols nb..nb+3 (both matrices per thread)
  const int qk = tid >> 4;
  const int qn = tid & 15;
  const int k0 = qk * 4;
  const int nb = qn * 4;
  const int cB = qk >> 1;
  const int bOff = (k0 & 4) * 2;             // byte offset {0,8} inside 16B slot
  const float* w1p = w1 + (size_t)e * H_DIM * I_DIM + n0 + nb;
  const float* w3p = w3 + (size_t)e * H_DIM * I_DIM + n0 + nb;

  f32x4 acc1[4][4] = {};
  f32x4 acc3[4][4] = {};
  F4U4 fA[8];
  f32x4 fB1[4], fB3[4];

  // prologue: issue kt=0 loads
  #pragma unroll
  for (int q = 0; q < 8; ++q) LOADF4(fA[q].f, xrow + q * 16);
  #pragma unroll
  for (int j = 0; j < 4; ++j) LOADF4(fB1[j], w1p + (size_t)(k0 + j) * I_DIM);
  #pragma unroll
  for (int j = 0; j < 4; ++j) LOADF4(fB3[j], w3p + (size_t)(k0 + j) * I_DIM);

  char* const sAc = (char*)sA;
  char* const sB1c = (char*)sB1;
  char* const sB3c = (char*)sB3;

  for (int kt = 0; kt < H_DIM / 64; ++kt) {
    WAITV0();
    // write A (already bf16 -- straight b128 stores)
    #pragma unroll
    for (int q = 0; q < 8; ++q) {
      unsigned int slot = (unsigned)(q ^ (tid & 7));
      *(uint4*)(sAc + tid * 128 + slot * 16) = fA[q].u;
    }
    // pack + write B1/B3
    #pragma unroll
    for (int j = 0; j < 4; ++j) {
      int n = nb + j;
      unsigned int o16 = (unsigned)((cB * 64 + n) << 4) ^ (unsigned)(((n >> 3) & 7) << 4);
      uint2 p1 = make_uint2(pack2bf(fB1[0][j], fB1[1][j]), pack2bf(fB1[2][j], fB1[3][j]));
      *(uint2*)(sB1c + o16 + bOff) = p1;
      uint2 p3 = make_uint2(pack2bf(fB3[0][j], fB3[1][j]), pack2bf(fB3[2][j], fB3[3][j]));
      *(uint2*)(sB3c + o16 + bOff) = p3;
    }
    // issue next-tile loads: stay in flight across both barriers + MFMA
    if (kt < H_DIM / 64 - 1) {
      const char* xn = xrow + (kt + 1) * 128;
      #pragma unroll
      for (int q = 0; q < 8; ++q) LOADF4(fA[q].f, xn + q * 16);
      const float* b1n = w1p + (size_t)((kt + 1) * 64 + k0) * I_DIM;
      const float* b3n = w3p + (size_t)((kt + 1) * 64 + k0) * I_DIM;
      #pragma unroll
      for (int j = 0; j < 4; ++j) LOADF4(fB1[j], b1n + (size_t)j * I_DIM);
      #pragma unroll
      for (int j = 0; j < 4; ++j) LOADF4(fB3[j], b3n + (size_t)j * I_DIM);
    }
    BAR_LGKM();
    // MFMA: wave covers rows wv*64..wv*64+63, all 64 cols
    #pragma unroll
    for (int ks = 0; ks < 2; ++ks) {
      bf16x8 af[4];
      #pragma unroll
      for (int mi = 0; mi < 4; ++mi) {
        int m = wv * 64 + mi * 16 + l15;
        U4B8 t; t.u = *(const uint4*)(sAc + m * 128 + (((ks * 4 + lhi) ^ (m & 7)) << 4));
        af[mi] = t.b;
      }
      #pragma unroll
      for (int ni = 0; ni < 4; ++ni) {
        int n = ni * 16 + l15;
        int c = ks * 4 + lhi;
        unsigned int o = (unsigned)((c * 64 + n) << 4) ^ (unsigned)(((n >> 3) & 7) << 4);
        U4B8 t1; t1.u = *(const uint4*)(sB1c + o);
        U4B8 t3; t3.u = *(const uint4*)(sB3c + o);
        #pragma unroll
        for (int mi = 0; mi < 4; ++mi) {
          acc1[mi][ni] = __builtin_amdgcn_mfma_f32_16x16x32_bf16(af[mi], t1.b, acc1[mi][ni], 0, 0, 0);
          acc3[mi][ni] = __builtin_amdgcn_mfma_f32_16x16x32_bf16(af[mi], t3.b, acc3[mi][ni], 0, 0, 0);
        }
      }
    }
    BAR_FREE();
  }

  // epilogue: act = silu(g) * u * wt (bf16)
  #pragma unroll
  for (int mi = 0; mi < 4; ++mi) {
    #pragma unroll
    for (int j = 0; j < 4; ++j) {
      int row = wv * 64 + mi * 16 + lhi * 4 + j;
      if (rt * 256 + row < R) {
        float wt = s_wt[row];
        size_t rbase = (size_t)(r0 + rt * 256 + row) * I_DIM + n0;
        #pragma unroll
        for (int ni = 0; ni < 4; ++ni) {
          float g = acc1[mi][ni][j];
          float u = acc3[mi][ni][j];
          float a = g / (1.f + __expf(-g)) * u * wt;
          act[rbase + ni * 16 + l15] = (unsigned short)f2bf(a);
        }
      }
    }
  }
}

// ---------------- gemm2: out[tok] += act @ w2 ----------------
// BM=256 BN=64 BK=64; w2 streams once per expert.
// A: double-buffered global_load_lds (pre-swizzled source); B: asm prefetch.
__global__ __launch_bounds__(256, 2)
void gemm2_kernel(const unsigned short* __restrict__ act, const float* __restrict__ w2,
                  const int* __restrict__ off, const int* __restrict__ row_tok,
                  float* __restrict__ out)
{
  const int e = blockIdx.z;
  const int r0 = off[e];
  const int R = off[e + 1] - r0;
  const int rt = blockIdx.y;
  if (rt * 256 >= R) return;
  const int n0 = blockIdx.x * 64;

  __shared__ unsigned short sA2[2][256 * 64];  // 2 x 32KB, content col-swizzled
  __shared__ unsigned int sB[8 * 64 * 4];      // 8KB, swizzled
  __shared__ int s_tok[256];

  const int tid = threadIdx.x;
  {
    int r = rt * 256 + tid;
    int rr = (r < R) ? r : (R - 1);
    s_tok[tid] = row_tok[r0 + rr];
  }
  __syncthreads();

  const int lane = tid & 63;
  const int wv = tid >> 6;                 // wave = 64-row block
  const int l15 = lane & 15, lhi = lane >> 4;

  // A DMA map: wave-uniform LDS base + lane*16B; source pre-swizzled.
  // Each wave fills rows wv*64 .. wv*64+63 via 8 x gload_lds16 (8 rows each).
  const unsigned short* asrc[8];
  #pragma unroll
  for (int i = 0; i < 8; ++i) {
    int ar = wv * 64 + i * 8 + (lane >> 3);
    int g = rt * 256 + ar; if (g >= R) g = R - 1;
    asrc[i] = act + (size_t)(r0 + g) * I_DIM + (((lane & 7) ^ (ar & 7)) << 3);
  }

  // B staging map
  const int qk = tid >> 4;
  const int qn = tid & 15;
  const int k0 = qk * 4;
  const int nb = qn * 4;
  const int cB = qk >> 1;
  const int bOff = (k0 & 4) * 2;
  const float* w2p = w2 + (size_t)e * I_DIM * H_DIM + n0 + nb;

  f32x4 acc[4][4] = {};
  f32x4 fB[4];

  // prologue: DMA A(0) -> buf0, issue B(0)
  {
    unsigned short* dst = &sA2[0][wv * 64 * 64];
    #pragma unroll
    for (int i = 0; i < 8; ++i) gload_lds16(asrc[i], dst + i * 8 * 64);
  }
  #pragma unroll
  for (int j = 0; j < 4; ++j) LOADF4(fB[j], w2p + (size_t)(k0 + j) * H_DIM);

  char* const sBc = (char*)sB;

  for (int kt = 0; kt < I_DIM / 64; ++kt) {
    WAITV0();                        // B(kt) + DMA(kt) complete (per-wave)
    #pragma unroll
    for (int j = 0; j < 4; ++j) {
      int n = nb + j;
      unsigned int o16 = (unsigned)((cB * 64 + n) << 4) ^ (unsigned)(((n >> 3) & 7) << 4);
      uint2 p = make_uint2(pack2bf(fB[0][j], fB[1][j]), pack2bf(fB[2][j], fB[3][j]));
      *(uint2*)(sBc + o16 + bOff) = p;
    }
    // issue B(kt+1) (register dest -> safe pre-barrier)
    if (kt < I_DIM / 64 - 1) {
      const float* bn = w2p + (size_t)((kt + 1) * 64 + k0) * H_DIM;
      #pragma unroll
      for (int j = 0; j < 4; ++j) LOADF4(fB[j], bn + (size_t)j * H_DIM);
    }
    BAR_LGKM();
    // DMA A(kt+1) into other buffer: safe only after barrier (all waves
    // finished MFMA(kt-1) reads of that buffer)
    if (kt < I_DIM / 64 - 1) {
      unsigned short* dst = &sA2[(kt + 1) & 1][wv * 64 * 64];
      #pragma unroll
      for (int i = 0; i < 8; ++i) gload_lds16(asrc[i] + (kt + 1) * 64, dst + i * 8 * 64);
    }
    // MFMA on buf[kt&1] + sB
    const char* sAb = (const char*)&sA2[kt & 1][0];
    #pragma unroll
    for (int ks = 0; ks < 2; ++ks) {
      bf16x8 af[4];
      #pragma unroll
      for (int mi = 0; mi < 4; ++mi) {
        int m = wv * 64 + mi * 16 + l15;
        U4B8 t;
        t.u = *(const uint4*)(sAb + m * 128 + (((ks * 4 + lhi) ^ (m & 7)) << 4));
        af[mi] = t.b;
      }
      #pragma unroll
      for (int ni = 0; ni < 4; ++ni) {
        int n = ni * 16 + l15;
        int c = ks * 4 + lhi;
        unsigned int o = (unsigned)((c * 64 + n) << 4) ^ (unsigned)(((n >> 3) & 7) << 4);
        U4B8 tb; tb.u = *(const uint4*)(sBc + o);
        #pragma unroll
        for (int mi = 0; mi < 4; ++mi)
          acc[mi][ni] = __builtin_amdgcn_mfma_f32_16x16x32_bf16(af[mi], tb.b, acc[mi][ni], 0, 0, 0);
      }
    }
    BAR_FREE();
  }

  // epilogue: weighted scatter-add
  #pragma unroll
  for (int mi = 0; mi < 4; ++mi) {
    #pragma unroll
    for (int j = 0; j < 4; ++j) {
      int row = wv * 64 + mi * 16 + lhi * 4 + j;
      if (rt * 256 + row < R) {
        float* ob = out + (size_t)s_tok[row] * H_DIM + n0;
        #pragma unroll
        for (int ni = 0; ni < 4; ++ni) {
          atomicAdd(ob + ni * 16 + l15, acc[mi][ni][j]);
        }
      }
    }
  }
}

extern "C" void kernel_launch(void* const* d_in, const int* in_sizes, int n_in,
                              void* d_out, int out_size, void* d_ws, size_t ws_size,
                              hipStream_t stream)
{
  const float* hs = (const float*)d_in[0];
  const float* gw = (const float*)d_in[1];
  const float* eb = (const float*)d_in[2];
  const float* w1 = (const float*)d_in[3];
  const float* w3 = (const float*)d_in[4];
  const float* w2 = (const float*)d_in[5];
  float* out = (float*)d_out;

  char* ws = (char*)d_ws;
  int*   tk_id   = (int*)(ws);                          // 49152 B
  float* tk_w    = (float*)(ws + 49152);                // 49152 B
  int*   off     = (int*)(ws + 98304);                  // 512 B (65 used)
  int*   row_tok = (int*)(ws + 98816);                  // 49152 B
  float* row_wt  = (float*)(ws + 147968);               // 49152 B
  unsigned short* xb  = (unsigned short*)(ws + 197120); // 4 MB bf16 hs
  unsigned short* act = (unsigned short*)(ws + 197120 + 4194304); // 12.58 MB

  hipMemsetAsync(out, 0, (size_t)T_TOK * H_DIM * sizeof(float), stream);
  hipLaunchKernelGGL(router_kernel, dim3(T_TOK), dim3(64), 0, stream,
                     hs, gw, eb, tk_id, tk_w, xb);
  hipLaunchKernelGGL(build_rows_kernel, dim3(1), dim3(1024), 0, stream,
                     tk_id, tk_w, off, row_tok, row_wt);
  hipLaunchKernelGGL(gemm1_kernel, dim3(8, 8, E_NUM), dim3(256), 0, stream,
                     xb, w1, w3, off, row_tok, row_wt, act);
  hipLaunchKernelGGL(gemm2_kernel, dim3(16, 8, E_NUM), dim3(256), 0, stream,
                     act, w2, off, row_tok, out);
}

// Round 2
// 372.676 us; speedup vs baseline: 1.2103x; 1.2103x over previous
//
#include <hip/hip_runtime.h>
#include <hip/hip_bf16.h>

#define T_TOK 2048
#define H_DIM 1024
#define I_DIM 512
#define E_NUM 64
#define TOPK  6
#define NROWS (T_TOK * TOPK)

typedef __attribute__((ext_vector_type(8))) short bf16x8;
typedef __attribute__((ext_vector_type(4))) float f32x4;

union U4B8 { uint4 u; bf16x8 b; };

__device__ __forceinline__ unsigned int f2bf(float x) {
  unsigned int u = __float_as_uint(x);
  return (u + 0x7fffu + ((u >> 16) & 1u)) >> 16;   // RNE
}
__device__ __forceinline__ unsigned int pack2bf(float lo, float hi) {
  __hip_bfloat162 h = __float22bfloat162_rn(make_float2(lo, hi));
  return *reinterpret_cast<unsigned int*>(&h);     // v_cvt_pk_bf16_f32
}

// volatile asm load: compiler cannot sink it to the use site -> true prefetch
#define LOADF4(dst, p) \
  asm volatile("global_load_dwordx4 %0, %1, off" : "=v"(dst) : "v"(p))

#define WAITV0() do { asm volatile("s_waitcnt vmcnt(0)" ::: "memory"); \
  __builtin_amdgcn_sched_barrier(0); } while (0)

// producer barrier: drain LDS writes only; vmem loads stay in flight
#define BAR_LGKM() do { __builtin_amdgcn_sched_barrier(0); \
  asm volatile("s_waitcnt lgkmcnt(0)\n\ts_barrier" ::: "memory"); \
  __builtin_amdgcn_sched_barrier(0); } while (0)

// consumer barrier: no waitcnt at all
#define BAR_FREE() do { __builtin_amdgcn_sched_barrier(0); \
  asm volatile("s_barrier" ::: "memory"); \
  __builtin_amdgcn_sched_barrier(0); } while (0)

__device__ __forceinline__ void gload_lds16(const void* gsrc, void* ldst) {
  __builtin_amdgcn_global_load_lds(
      (const __attribute__((address_space(1))) unsigned int*)gsrc,
      (__attribute__((address_space(3))) unsigned int*)ldst, 16, 0, 0);
}

// ---------------- router: logits + sigmoid + grouped top-k + hs->bf16 ------
__global__ __launch_bounds__(64)
void router_kernel(const float* __restrict__ hs, const float* __restrict__ gw,
                   const float* __restrict__ eb, int* __restrict__ tk_id,
                   float* __restrict__ tk_w, unsigned short* __restrict__ xb)
{
  const int t = blockIdx.x;
  const int lane = threadIdx.x;          // lane == expert
  __shared__ float sh[H_DIM];
  const float4* hrow = (const float4*)(hs + (size_t)t * H_DIM);
  float4* sh4 = (float4*)sh;
  for (int i = lane; i < H_DIM / 4; i += 64) sh4[i] = hrow[i];
  __syncthreads();

  // emit bf16 copy of this token's row (consumed by gemm1 A-staging)
  {
    uint4* xrow = (uint4*)(xb + (size_t)t * H_DIM);
    #pragma unroll
    for (int f = 0; f < 2; ++f) {
      int i = lane + f * 64;                    // uint4 index 0..127
      float4 a = sh4[i * 2], b = sh4[i * 2 + 1];
      uint4 o;
      o.x = pack2bf(a.x, a.y); o.y = pack2bf(a.z, a.w);
      o.z = pack2bf(b.x, b.y); o.w = pack2bf(b.z, b.w);
      xrow[i] = o;
    }
  }

  const float* w = gw + (size_t)lane * H_DIM;
  float acc = 0.f;
  for (int k = 0; k < H_DIM; k += 4) {
    float4 wv = *(const float4*)(w + k);
    acc += sh[k] * wv.x + sh[k + 1] * wv.y + sh[k + 2] * wv.z + sh[k + 3] * wv.w;
  }
  const float score = 1.f / (1.f + expf(-acc));
  const float sfc = score + eb[lane];

  float m1v = sfc; int m1i = lane;
  #pragma unroll
  for (int d = 1; d < 8; d <<= 1) {
    float ov = __shfl_xor(m1v, d); int oi = __shfl_xor(m1i, d);
    if (ov > m1v || (ov == m1v && oi < m1i)) { m1v = ov; m1i = oi; }
  }
  float v2 = (lane == m1i) ? -INFINITY : sfc;
  #pragma unroll
  for (int d = 1; d < 8; d <<= 1) v2 = fmaxf(v2, __shfl_xor(v2, d));
  const float gscore = m1v + v2;

  const int myg = lane >> 3;
  int rank = 0;
  #pragma unroll
  for (int g = 0; g < 8; ++g) {
    float gs = __shfl(gscore, g * 8);
    if (gs > gscore || (gs == gscore && g < myg)) rank++;
  }
  float mv = (rank < 4) ? sfc : -INFINITY;

  int isel[TOPK]; float wsel[TOPK]; float wsum = 0.f;
  #pragma unroll
  for (int j = 0; j < TOPK; ++j) {
    float av = mv; int ai = lane;
    #pragma unroll
    for (int d = 1; d < 64; d <<= 1) {
      float ov = __shfl_xor(av, d); int oi = __shfl_xor(ai, d);
      if (ov > av || (ov == av && oi < ai)) { av = ov; ai = oi; }
    }
    float wj = __shfl(score, ai);
    isel[j] = ai; wsel[j] = wj; wsum += wj;
    if (lane == ai) mv = -INFINITY;
  }
  if (lane == 0) {
    float inv = 1.f / wsum;
    #pragma unroll
    for (int j = 0; j < TOPK; ++j) {
      tk_id[t * TOPK + j] = isel[j];
      tk_w[t * TOPK + j] = wsel[j] * inv;
    }
  }
}

// ---------------- counting-sort rows by expert ----------------
__global__ __launch_bounds__(1024)
void build_rows_kernel(const int* __restrict__ tk_id, const float* __restrict__ tk_w,
                       int* __restrict__ off, int* __restrict__ row_tok,
                       float* __restrict__ row_wt)
{
  __shared__ int cnt[E_NUM];
  __shared__ int base[E_NUM];
  const int tid = threadIdx.x;
  if (tid < E_NUM) cnt[tid] = 0;
  __syncthreads();
  for (int i = tid; i < NROWS; i += 1024) atomicAdd(&cnt[tk_id[i]], 1);
  __syncthreads();
  if (tid == 0) {
    int s = 0;
    for (int e = 0; e < E_NUM; ++e) { base[e] = s; off[e] = s; s += cnt[e]; }
    off[E_NUM] = s;
  }
  __syncthreads();
  if (tid < E_NUM) cnt[tid] = base[tid];
  __syncthreads();
  for (int i = tid; i < NROWS; i += 1024) {
    int e = tk_id[i];
    int p = atomicAdd(&cnt[e], 1);
    row_tok[p] = i / TOPK;
    row_wt[p] = tk_w[i];
  }
}

// ---------------- gemm1: act = silu(X@w1) * (X@w3) * wt  (bf16 out) --------
// BM=256 BN=64 BK=64, 512 threads / 8 waves (wave = 64 rows x 32 cols).
// Weights stream EXACTLY ONCE per expert. A: global_load_lds dbuf from bf16 xb
// (pre-swizzled per-lane source); B: reg prefetch, thread-halves split w1/w3.
// LDS = 64K(A dbuf) + 8K + 8K = 80KB -> 2 blocks/CU.
__global__ __launch_bounds__(512, 4)
void gemm1_kernel(const unsigned short* __restrict__ xb, const float* __restrict__ w1,
                  const float* __restrict__ w3, const int* __restrict__ off,
                  const int* __restrict__ row_tok, const float* __restrict__ row_wt,
                  unsigned short* __restrict__ act)
{
  const int e = blockIdx.z;
  const int r0 = off[e];
  const int R = off[e + 1] - r0;
  const int rt = blockIdx.y;
  if (rt * 256 >= R) return;
  const int n0 = blockIdx.x * 64;

  __shared__ unsigned short sA2[2][256 * 64];  // 64KB dbuf, per-row chunk swizzle
  __shared__ unsigned int sB1[8 * 64 * 4];     // 8KB [c=k>>3][n] 16B slots, swizzled
  __shared__ unsigned int sB3[8 * 64 * 4];     // 8KB

  const int tid = threadIdx.x;
  const int lane = tid & 63;
  const int wv = tid >> 6;                 // 0..7
  const int wm = wv >> 1, wn = wv & 1;     // wave tile: rows wm*64, cols wn*32
  const int l15 = lane & 15, lhi = lane >> 4;

  // A DMA map: wave fills rows wv*32..wv*32+31, 4 DMAs of 8 rows each.
  // LDS linear; source chunk pre-swizzled: slot s of row ar holds chunk s^(ar&7).
  const unsigned short* asrc[4];
  #pragma unroll
  for (int i = 0; i < 4; ++i) {
    int ar = wv * 32 + i * 8 + (lane >> 3);
    int g = rt * 256 + ar; if (g >= R) g = R - 1;
    int tok = row_tok[r0 + g];
    asrc[i] = xb + (size_t)tok * H_DIM + (((lane & 7) ^ (ar & 7)) << 3);
  }

  // B staging: tid<256 -> w1, tid>=256 -> w3 (wave-uniform split)
  const int ht = tid & 255;
  const int qk = ht >> 4;                  // 0..15
  const int qn = ht & 15;
  const int k0 = qk * 4;
  const int nb = qn * 4;
  const int cB = qk >> 1;
  const int bOff = (k0 & 4) * 2;           // byte offset {0,8} inside 16B slot
  const float* wp = ((tid < 256) ? w1 : w3) + (size_t)e * H_DIM * I_DIM + n0 + nb;
  char* const sBw = (char*)((tid < 256) ? sB1 : sB3);

  f32x4 acc1[4][2] = {};
  f32x4 acc3[4][2] = {};
  f32x4 fB[4];

  // prologue: DMA A(0) -> buf0, issue B(0)
  {
    unsigned short* dst = &sA2[0][(wv * 32) * 64];
    #pragma unroll
    for (int i = 0; i < 4; ++i) gload_lds16(asrc[i], dst + i * 8 * 64);
  }
  #pragma unroll
  for (int j = 0; j < 4; ++j) LOADF4(fB[j], wp + (size_t)(k0 + j) * I_DIM);

  char* const sB1c = (char*)sB1;
  char* const sB3c = (char*)sB3;

  for (int kt = 0; kt < H_DIM / 64; ++kt) {
    WAITV0();                              // fB(kt) + DMA(kt) complete
    // pack + write B tile (each thread: one matrix)
    #pragma unroll
    for (int j = 0; j < 4; ++j) {
      int n = nb + j;
      unsigned int o16 = (unsigned)((cB * 64 + n) << 4) ^ (unsigned)(((n >> 3) & 7) << 4);
      uint2 p = make_uint2(pack2bf(fB[0][j], fB[1][j]), pack2bf(fB[2][j], fB[3][j]));
      *(uint2*)(sBw + o16 + bOff) = p;
    }
    // issue B(kt+1): register dest -> safe pre-barrier, in flight across MFMA
    if (kt < H_DIM / 64 - 1) {
      const float* bn = wp + (size_t)((kt + 1) * 64 + k0) * I_DIM;
      #pragma unroll
      for (int j = 0; j < 4; ++j) LOADF4(fB[j], bn + (size_t)j * I_DIM);
    }
    BAR_LGKM();
    // DMA A(kt+1) into other buffer (all waves past MFMA(kt-1) reads)
    if (kt < H_DIM / 64 - 1) {
      unsigned short* dst = &sA2[(kt + 1) & 1][(wv * 32) * 64];
      #pragma unroll
      for (int i = 0; i < 4; ++i) gload_lds16(asrc[i] + (kt + 1) * 64, dst + i * 8 * 64);
    }
    // MFMA on buf[kt&1] + sB1/sB3
    const char* sAb = (const char*)&sA2[kt & 1][0];
    __builtin_amdgcn_s_setprio(1);
    #pragma unroll
    for (int ks = 0; ks < 2; ++ks) {
      bf16x8 af[4];
      #pragma unroll
      for (int mi = 0; mi < 4; ++mi) {
        int m = wm * 64 + mi * 16 + l15;
        U4B8 t; t.u = *(const uint4*)(sAb + m * 128 + (((ks * 4 + lhi) ^ (m & 7)) << 4));
        af[mi] = t.b;
      }
      #pragma unroll
      for (int ni = 0; ni < 2; ++ni) {
        int n = wn * 32 + ni * 16 + l15;
        int c = ks * 4 + lhi;
        unsigned int o = (unsigned)((c * 64 + n) << 4) ^ (unsigned)(((n >> 3) & 7) << 4);
        U4B8 t1; t1.u = *(const uint4*)(sB1c + o);
        U4B8 t3; t3.u = *(const uint4*)(sB3c + o);
        #pragma unroll
        for (int mi = 0; mi < 4; ++mi) {
          acc1[mi][ni] = __builtin_amdgcn_mfma_f32_16x16x32_bf16(af[mi], t1.b, acc1[mi][ni], 0, 0, 0);
          acc3[mi][ni] = __builtin_amdgcn_mfma_f32_16x16x32_bf16(af[mi], t3.b, acc3[mi][ni], 0, 0, 0);
        }
      }
    }
    __builtin_amdgcn_s_setprio(0);
    BAR_FREE();
  }

  // epilogue: act = silu(g) * u * wt (bf16)
  #pragma unroll
  for (int mi = 0; mi < 4; ++mi) {
    #pragma unroll
    for (int j = 0; j < 4; ++j) {
      int row = wm * 64 + mi * 16 + lhi * 4 + j;
      int rg = rt * 256 + row;
      if (rg < R) {
        float wt = row_wt[r0 + rg];
        size_t rbase = (size_t)(r0 + rg) * I_DIM + n0 + wn * 32;
        #pragma unroll
        for (int ni = 0; ni < 2; ++ni) {
          float g = acc1[mi][ni][j];
          float u = acc3[mi][ni][j];
          float a = g / (1.f + __expf(-g)) * u * wt;
          act[rbase + ni * 16 + l15] = (unsigned short)f2bf(a);
        }
      }
    }
  }
}

// ---------------- gemm2: out[tok] += act @ w2 ----------------
// BM=256 BN=64 BK=64, 512 threads / 8 waves; w2 streams once per expert.
// A: global_load_lds dbuf (pre-swizzled source); B: reg prefetch.
__global__ __launch_bounds__(512, 4)
void gemm2_kernel(const unsigned short* __restrict__ act, const float* __restrict__ w2,
                  const int* __restrict__ off, const int* __restrict__ row_tok,
                  float* __restrict__ out)
{
  const int e = blockIdx.z;
  const int r0 = off[e];
  const int R = off[e + 1] - r0;
  const int rt = blockIdx.y;
  if (rt * 256 >= R) return;
  const int n0 = blockIdx.x * 64;

  __shared__ unsigned short sA2[2][256 * 64];  // 64KB dbuf
  __shared__ unsigned int sB[8 * 64 * 4];      // 8KB, swizzled
  __shared__ int s_tok[256];

  const int tid = threadIdx.x;
  if (tid < 256) {
    int r = rt * 256 + tid;
    int rr = (r < R) ? r : (R - 1);
    s_tok[tid] = row_tok[r0 + rr];
  }
  __syncthreads();

  const int lane = tid & 63;
  const int wv = tid >> 6;
  const int wm = wv >> 1, wn = wv & 1;
  const int l15 = lane & 15, lhi = lane >> 4;

  // A DMA map: wave fills rows wv*32..+31, 4 DMAs of 8 rows
  const unsigned short* asrc[4];
  #pragma unroll
  for (int i = 0; i < 4; ++i) {
    int ar = wv * 32 + i * 8 + (lane >> 3);
    int g = rt * 256 + ar; if (g >= R) g = R - 1;
    asrc[i] = act + (size_t)(r0 + g) * I_DIM + (((lane & 7) ^ (ar & 7)) << 3);
  }

  // B staging map: 512 threads, 2 rows each (k0, k0+1), 4 cols
  const int qk2 = tid >> 4;                // 0..31
  const int k0 = qk2 * 2;
  const int nb = (tid & 15) * 4;
  const int cB2 = qk2 >> 2;                // k0>>3
  const int pr = qk2 & 3;                  // k-pair index in slot
  const float* w2p = w2 + (size_t)e * I_DIM * H_DIM + n0 + nb;

  f32x4 acc[4][2] = {};
  f32x4 fB[2];

  // prologue: DMA A(0) -> buf0, issue B(0)
  {
    unsigned short* dst = &sA2[0][(wv * 32) * 64];
    #pragma unroll
    for (int i = 0; i < 4; ++i) gload_lds16(asrc[i], dst + i * 8 * 64);
  }
  #pragma unroll
  for (int j = 0; j < 2; ++j) LOADF4(fB[j], w2p + (size_t)(k0 + j) * H_DIM);

  char* const sBc = (char*)sB;

  for (int kt = 0; kt < I_DIM / 64; ++kt) {
    WAITV0();                              // fB(kt) + DMA(kt) complete
    #pragma unroll
    for (int j = 0; j < 4; ++j) {
      int n = nb + j;
      unsigned int o16 = (unsigned)((cB2 * 64 + n) << 4) ^ (unsigned)(((n >> 3) & 7) << 4);
      *(unsigned int*)(sBc + o16 + pr * 4) = pack2bf(fB[0][j], fB[1][j]);
    }
    if (kt < I_DIM / 64 - 1) {
      const float* bn = w2p + (size_t)((kt + 1) * 64 + k0) * H_DIM;
      #pragma unroll
      for (int j = 0; j < 2; ++j) LOADF4(fB[j], bn + (size_t)j * H_DIM);
    }
    BAR_LGKM();
    if (kt < I_DIM / 64 - 1) {
      unsigned short* dst = &sA2[(kt + 1) & 1][(wv * 32) * 64];
      #pragma unroll
      for (int i = 0; i < 4; ++i) gload_lds16(asrc[i] + (kt + 1) * 64, dst + i * 8 * 64);
    }
    const char* sAb = (const char*)&sA2[kt & 1][0];
    __builtin_amdgcn_s_setprio(1);
    #pragma unroll
    for (int ks = 0; ks < 2; ++ks) {
      bf16x8 af[4];
      #pragma unroll
      for (int mi = 0; mi < 4; ++mi) {
        int m = wm * 64 + mi * 16 + l15;
        U4B8 t;
        t.u = *(const uint4*)(sAb + m * 128 + (((ks * 4 + lhi) ^ (m & 7)) << 4));
        af[mi] = t.b;
      }
      #pragma unroll
      for (int ni = 0; ni < 2; ++ni) {
        int n = wn * 32 + ni * 16 + l15;
        int c = ks * 4 + lhi;
        unsigned int o = (unsigned)((c * 64 + n) << 4) ^ (unsigned)(((n >> 3) & 7) << 4);
        U4B8 tb; tb.u = *(const uint4*)(sBc + o);
        #pragma unroll
        for (int mi = 0; mi < 4; ++mi)
          acc[mi][ni] = __builtin_amdgcn_mfma_f32_16x16x32_bf16(af[mi], tb.b, acc[mi][ni], 0, 0, 0);
      }
    }
    __builtin_amdgcn_s_setprio(0);
    BAR_FREE();
  }

  // epilogue: scatter-add to token rows
  #pragma unroll
  for (int mi = 0; mi < 4; ++mi) {
    #pragma unroll
    for (int j = 0; j < 4; ++j) {
      int row = wm * 64 + mi * 16 + lhi * 4 + j;
      if (rt * 256 + row < R) {
        float* ob = out + (size_t)s_tok[row] * H_DIM + n0 + wn * 32;
        #pragma unroll
        for (int ni = 0; ni < 2; ++ni) {
          atomicAdd(ob + ni * 16 + l15, acc[mi][ni][j]);
        }
      }
    }
  }
}

extern "C" void kernel_launch(void* const* d_in, const int* in_sizes, int n_in,
                              void* d_out, int out_size, void* d_ws, size_t ws_size,
                              hipStream_t stream)
{
  const float* hs = (const float*)d_in[0];
  const float* gw = (const float*)d_in[1];
  const float* eb = (const float*)d_in[2];
  const float* w1 = (const float*)d_in[3];
  const float* w3 = (const float*)d_in[4];
  const float* w2 = (const float*)d_in[5];
  float* out = (float*)d_out;

  char* ws = (char*)d_ws;
  int*   tk_id   = (int*)(ws);                          // 49152 B
  float* tk_w    = (float*)(ws + 49152);                // 49152 B
  int*   off     = (int*)(ws + 98304);                  // 512 B (65 used)
  int*   row_tok = (int*)(ws + 98816);                  // 49152 B
  float* row_wt  = (float*)(ws + 147968);               // 49152 B
  unsigned short* xb  = (unsigned short*)(ws + 197120); // 4 MB bf16 hs
  unsigned short* act = (unsigned short*)(ws + 197120 + 4194304); // 12.58 MB

  hipMemsetAsync(out, 0, (size_t)T_TOK * H_DIM * sizeof(float), stream);
  hipLaunchKernelGGL(router_kernel, dim3(T_TOK), dim3(64), 0, stream,
                     hs, gw, eb, tk_id, tk_w, xb);
  hipLaunchKernelGGL(build_rows_kernel, dim3(1), dim3(1024), 0, stream,
                     tk_id, tk_w, off, row_tok, row_wt);
  hipLaunchKernelGGL(gemm1_kernel, dim3(8, 8, E_NUM), dim3(512), 0, stream,
                     xb, w1, w3, off, row_tok, row_wt, act);
  hipLaunchKernelGGL(gemm2_kernel, dim3(16, 8, E_NUM), dim3(512), 0, stream,
                     act, w2, off, row_tok, out);
}

// Round 5
// 246.201 us; speedup vs baseline: 1.8321x; 1.5137x over previous
//
#include <hip/hip_runtime.h>
#include <hip/hip_bf16.h>

#define T_TOK 2048
#define H_DIM 1024
#define I_DIM 512
#define E_NUM 64
#define TOPK  6
#define NROWS (T_TOK * TOPK)

typedef __attribute__((ext_vector_type(8))) short bf16x8;
typedef __attribute__((ext_vector_type(4))) float f32x4;

union U4B8 { uint4 u; bf16x8 b; };

__device__ __forceinline__ unsigned int f2bf(float x) {
  unsigned int u = __float_as_uint(x);
  return (u + 0x7fffu + ((u >> 16) & 1u)) >> 16;   // RNE
}
__device__ __forceinline__ unsigned int pack2bf(float lo, float hi) {
  __hip_bfloat162 h = __float22bfloat162_rn(make_float2(lo, hi));
  return *reinterpret_cast<unsigned int*>(&h);     // v_cvt_pk_bf16_f32
}

// volatile asm load: compiler cannot sink it to the use site -> true prefetch
#define LOADF4(dst, p) \
  asm volatile("global_load_dwordx4 %0, %1, off" : "=v"(dst) : "v"(p))

#define WAITV0() do { asm volatile("s_waitcnt vmcnt(0)" ::: "memory"); \
  __builtin_amdgcn_sched_barrier(0); } while (0)

// producer barrier: drain LDS writes only; vmem loads stay in flight
#define BAR_LGKM() do { __builtin_amdgcn_sched_barrier(0); \
  asm volatile("s_waitcnt lgkmcnt(0)\n\ts_barrier" ::: "memory"); \
  __builtin_amdgcn_sched_barrier(0); } while (0)

// consumer barrier: no waitcnt at all
#define BAR_FREE() do { __builtin_amdgcn_sched_barrier(0); \
  asm volatile("s_barrier" ::: "memory"); \
  __builtin_amdgcn_sched_barrier(0); } while (0)

__device__ __forceinline__ void gload_lds16(const void* gsrc, void* ldst) {
  __builtin_amdgcn_global_load_lds(
      (const __attribute__((address_space(1))) unsigned int*)gsrc,
      (__attribute__((address_space(3))) unsigned int*)ldst, 16, 0, 0);
}

// ---------------- router: logits + sigmoid + grouped top-k + hs->bf16 ------
__global__ __launch_bounds__(64)
void router_kernel(const float* __restrict__ hs, const float* __restrict__ gw,
                   const float* __restrict__ eb, int* __restrict__ tk_id,
                   float* __restrict__ tk_w, unsigned short* __restrict__ xb)
{
  const int t = blockIdx.x;
  const int lane = threadIdx.x;          // lane == expert
  __shared__ float sh[H_DIM];
  const float4* hrow = (const float4*)(hs + (size_t)t * H_DIM);
  float4* sh4 = (float4*)sh;
  for (int i = lane; i < H_DIM / 4; i += 64) sh4[i] = hrow[i];
  __syncthreads();

  // emit bf16 copy of this token's row (consumed by gemm1 A-staging)
  {
    uint4* xrow = (uint4*)(xb + (size_t)t * H_DIM);
    #pragma unroll
    for (int f = 0; f < 2; ++f) {
      int i = lane + f * 64;                    // uint4 index 0..127
      float4 a = sh4[i * 2], b = sh4[i * 2 + 1];
      uint4 o;
      o.x = pack2bf(a.x, a.y); o.y = pack2bf(a.z, a.w);
      o.z = pack2bf(b.x, b.y); o.w = pack2bf(b.z, b.w);
      xrow[i] = o;
    }
  }

  const float* w = gw + (size_t)lane * H_DIM;
  float acc = 0.f;
  for (int k = 0; k < H_DIM; k += 4) {
    float4 wv = *(const float4*)(w + k);
    acc += sh[k] * wv.x + sh[k + 1] * wv.y + sh[k + 2] * wv.z + sh[k + 3] * wv.w;
  }
  const float score = 1.f / (1.f + expf(-acc));
  const float sfc = score + eb[lane];

  float m1v = sfc; int m1i = lane;
  #pragma unroll
  for (int d = 1; d < 8; d <<= 1) {
    float ov = __shfl_xor(m1v, d); int oi = __shfl_xor(m1i, d);
    if (ov > m1v || (ov == m1v && oi < m1i)) { m1v = ov; m1i = oi; }
  }
  float v2 = (lane == m1i) ? -INFINITY : sfc;
  #pragma unroll
  for (int d = 1; d < 8; d <<= 1) v2 = fmaxf(v2, __shfl_xor(v2, d));
  const float gscore = m1v + v2;

  const int myg = lane >> 3;
  int rank = 0;
  #pragma unroll
  for (int g = 0; g < 8; ++g) {
    float gs = __shfl(gscore, g * 8);
    if (gs > gscore || (gs == gscore && g < myg)) rank++;
  }
  float mv = (rank < 4) ? sfc : -INFINITY;

  int isel[TOPK]; float wsel[TOPK]; float wsum = 0.f;
  #pragma unroll
  for (int j = 0; j < TOPK; ++j) {
    float av = mv; int ai = lane;
    #pragma unroll
    for (int d = 1; d < 64; d <<= 1) {
      float ov = __shfl_xor(av, d); int oi = __shfl_xor(ai, d);
      if (ov > av || (ov == av && oi < ai)) { av = ov; ai = oi; }
    }
    float wj = __shfl(score, ai);
    isel[j] = ai; wsel[j] = wj; wsum += wj;
    if (lane == ai) mv = -INFINITY;
  }
  if (lane == 0) {
    float inv = 1.f / wsum;
    #pragma unroll
    for (int j = 0; j < TOPK; ++j) {
      tk_id[t * TOPK + j] = isel[j];
      tk_w[t * TOPK + j] = wsel[j] * inv;
    }
  }
}

// ---------------- counting-sort rows by expert ----------------
__global__ __launch_bounds__(1024)
void build_rows_kernel(const int* __restrict__ tk_id, const float* __restrict__ tk_w,
                       int* __restrict__ off, int* __restrict__ row_tok,
                       float* __restrict__ row_wt)
{
  __shared__ int cnt[E_NUM];
  __shared__ int base[E_NUM];
  const int tid = threadIdx.x;
  if (tid < E_NUM) cnt[tid] = 0;
  __syncthreads();
  for (int i = tid; i < NROWS; i += 1024) atomicAdd(&cnt[tk_id[i]], 1);
  __syncthreads();
  if (tid == 0) {
    int s = 0;
    for (int e = 0; e < E_NUM; ++e) { base[e] = s; off[e] = s; s += cnt[e]; }
    off[E_NUM] = s;
  }
  __syncthreads();
  if (tid < E_NUM) cnt[tid] = base[tid];
  __syncthreads();
  for (int i = tid; i < NROWS; i += 1024) {
    int e = tk_id[i];
    int p = atomicAdd(&cnt[e], 1);
    row_tok[p] = i / TOPK;
    row_wt[p] = tk_w[i];
  }
}

// ---------------- gemm1: act = silu(X@w1) * (X@w3) * wt  (bf16 out) --------
// BM=256 BN=64 BK=64, 512 threads / 8 waves (wave = 64 rows x 32 cols).
// PROVEN Round-2 pipeline (A dbuf global_load_lds + WAITV0 + BAR_LGKM/FREE),
// single change: flattened grid x = ntile*64 + e so live blocks are a dense
// consecutive range -> even XCD/CU spread (R2 grid starved 7/8 of the CUs).
// LDS = 64K(A dbuf) + 8K + 8K = 80KB -> 2 blocks/CU.
__global__ __launch_bounds__(512, 4)
void gemm1_kernel(const unsigned short* __restrict__ xb, const float* __restrict__ w1,
                  const float* __restrict__ w3, const int* __restrict__ off,
                  const int* __restrict__ row_tok, const float* __restrict__ row_wt,
                  unsigned short* __restrict__ act)
{
  const int e = blockIdx.x & 63;
  const int n0 = (blockIdx.x >> 6) * 64;
  const int r0 = off[e];
  const int R = off[e + 1] - r0;
  const int rt = blockIdx.y;
  if (rt * 256 >= R) return;

  __shared__ unsigned short sA2[2][256 * 64];  // 64KB dbuf, per-row chunk swizzle
  __shared__ unsigned int sB1[8 * 64 * 4];     // 8KB [c=k>>3][n] 16B slots, swizzled
  __shared__ unsigned int sB3[8 * 64 * 4];     // 8KB

  const int tid = threadIdx.x;
  const int lane = tid & 63;
  const int wv = tid >> 6;                 // 0..7
  const int wm = wv >> 1, wn = wv & 1;     // wave tile: rows wm*64, cols wn*32
  const int l15 = lane & 15, lhi = lane >> 4;

  // A DMA map: wave fills rows wv*32..wv*32+31, 4 DMAs of 8 rows each.
  // LDS linear; source chunk pre-swizzled: slot s of row ar holds chunk s^(ar&7).
  const unsigned short* asrc[4];
  #pragma unroll
  for (int i = 0; i < 4; ++i) {
    int ar = wv * 32 + i * 8 + (lane >> 3);
    int g = rt * 256 + ar; if (g >= R) g = R - 1;
    int tok = row_tok[r0 + g];
    asrc[i] = xb + (size_t)tok * H_DIM + (((lane & 7) ^ (ar & 7)) << 3);
  }

  // B staging: tid<256 -> w1, tid>=256 -> w3 (wave-uniform split)
  const int ht = tid & 255;
  const int qk = ht >> 4;                  // 0..15
  const int qn = ht & 15;
  const int k0 = qk * 4;
  const int nb = qn * 4;
  const int cB = qk >> 1;
  const int bOff = (k0 & 4) * 2;           // byte offset {0,8} inside 16B slot
  const float* wp = ((tid < 256) ? w1 : w3) + (size_t)e * H_DIM * I_DIM + n0 + nb;
  char* const sBw = (char*)((tid < 256) ? sB1 : sB3);

  f32x4 acc1[4][2] = {};
  f32x4 acc3[4][2] = {};
  f32x4 fB[4];

  // prologue: DMA A(0) -> buf0, issue B(0)
  {
    unsigned short* dst = &sA2[0][(wv * 32) * 64];
    #pragma unroll
    for (int i = 0; i < 4; ++i) gload_lds16(asrc[i], dst + i * 8 * 64);
  }
  #pragma unroll
  for (int j = 0; j < 4; ++j) LOADF4(fB[j], wp + (size_t)(k0 + j) * I_DIM);

  char* const sB1c = (char*)sB1;
  char* const sB3c = (char*)sB3;

  for (int kt = 0; kt < H_DIM / 64; ++kt) {
    WAITV0();                              // fB(kt) + DMA(kt) complete
    // pack + write B tile (each thread: one matrix)
    #pragma unroll
    for (int j = 0; j < 4; ++j) {
      int n = nb + j;
      unsigned int o16 = (unsigned)((cB * 64 + n) << 4) ^ (unsigned)(((n >> 3) & 7) << 4);
      uint2 p = make_uint2(pack2bf(fB[0][j], fB[1][j]), pack2bf(fB[2][j], fB[3][j]));
      *(uint2*)(sBw + o16 + bOff) = p;
    }
    // issue B(kt+1): register dest -> safe pre-barrier, in flight across MFMA
    if (kt < H_DIM / 64 - 1) {
      const float* bn = wp + (size_t)((kt + 1) * 64 + k0) * I_DIM;
      #pragma unroll
      for (int j = 0; j < 4; ++j) LOADF4(fB[j], bn + (size_t)j * I_DIM);
    }
    BAR_LGKM();
    // DMA A(kt+1) into other buffer (all waves past MFMA(kt-1) reads)
    if (kt < H_DIM / 64 - 1) {
      unsigned short* dst = &sA2[(kt + 1) & 1][(wv * 32) * 64];
      #pragma unroll
      for (int i = 0; i < 4; ++i) gload_lds16(asrc[i] + (kt + 1) * 64, dst + i * 8 * 64);
    }
    // MFMA on buf[kt&1] + sB1/sB3
    const char* sAb = (const char*)&sA2[kt & 1][0];
    __builtin_amdgcn_s_setprio(1);
    #pragma unroll
    for (int ks = 0; ks < 2; ++ks) {
      bf16x8 af[4];
      #pragma unroll
      for (int mi = 0; mi < 4; ++mi) {
        int m = wm * 64 + mi * 16 + l15;
        U4B8 t; t.u = *(const uint4*)(sAb + m * 128 + (((ks * 4 + lhi) ^ (m & 7)) << 4));
        af[mi] = t.b;
      }
      #pragma unroll
      for (int ni = 0; ni < 2; ++ni) {
        int n = wn * 32 + ni * 16 + l15;
        int c = ks * 4 + lhi;
        unsigned int o = (unsigned)((c * 64 + n) << 4) ^ (unsigned)(((n >> 3) & 7) << 4);
        U4B8 t1; t1.u = *(const uint4*)(sB1c + o);
        U4B8 t3; t3.u = *(const uint4*)(sB3c + o);
        #pragma unroll
        for (int mi = 0; mi < 4; ++mi) {
          acc1[mi][ni] = __builtin_amdgcn_mfma_f32_16x16x32_bf16(af[mi], t1.b, acc1[mi][ni], 0, 0, 0);
          acc3[mi][ni] = __builtin_amdgcn_mfma_f32_16x16x32_bf16(af[mi], t3.b, acc3[mi][ni], 0, 0, 0);
        }
      }
    }
    __builtin_amdgcn_s_setprio(0);
    BAR_FREE();
  }

  // epilogue: act = silu(g) * u * wt (bf16)
  #pragma unroll
  for (int mi = 0; mi < 4; ++mi) {
    #pragma unroll
    for (int j = 0; j < 4; ++j) {
      int row = wm * 64 + mi * 16 + lhi * 4 + j;
      int rg = rt * 256 + row;
      if (rg < R) {
        float wt = row_wt[r0 + rg];
        size_t rbase = (size_t)(r0 + rg) * I_DIM + n0 + wn * 32;
        #pragma unroll
        for (int ni = 0; ni < 2; ++ni) {
          float g = acc1[mi][ni][j];
          float u = acc3[mi][ni][j];
          float a = g / (1.f + __expf(-g)) * u * wt;
          act[rbase + ni * 16 + l15] = (unsigned short)f2bf(a);
        }
      }
    }
  }
}

// ---------------- gemm2: out[tok] += act @ w2 ----------------
// BM=256 BN=64 BK=64, 512 threads / 8 waves; w2 streams once per expert.
// PROVEN Round-2 pipeline; single change: flattened grid (as gemm1).
// LDS = 64K + 8K + 1K -> 2 blocks/CU.
__global__ __launch_bounds__(512, 4)
void gemm2_kernel(const unsigned short* __restrict__ act, const float* __restrict__ w2,
                  const int* __restrict__ off, const int* __restrict__ row_tok,
                  float* __restrict__ out)
{
  const int e = blockIdx.x & 63;
  const int n0 = (blockIdx.x >> 6) * 64;
  const int r0 = off[e];
  const int R = off[e + 1] - r0;
  const int rt = blockIdx.y;
  if (rt * 256 >= R) return;

  __shared__ unsigned short sA2[2][256 * 64];  // 64KB dbuf
  __shared__ unsigned int sB[8 * 64 * 4];      // 8KB, swizzled
  __shared__ int s_tok[256];

  const int tid = threadIdx.x;
  if (tid < 256) {
    int r = rt * 256 + tid;
    int rr = (r < R) ? r : (R - 1);
    s_tok[tid] = row_tok[r0 + rr];
  }
  __syncthreads();

  const int lane = tid & 63;
  const int wv = tid >> 6;
  const int wm = wv >> 1, wn = wv & 1;
  const int l15 = lane & 15, lhi = lane >> 4;

  // A DMA map: wave fills rows wv*32..+31, 4 DMAs of 8 rows
  const unsigned short* asrc[4];
  #pragma unroll
  for (int i = 0; i < 4; ++i) {
    int ar = wv * 32 + i * 8 + (lane >> 3);
    int g = rt * 256 + ar; if (g >= R) g = R - 1;
    asrc[i] = act + (size_t)(r0 + g) * I_DIM + (((lane & 7) ^ (ar & 7)) << 3);
  }

  // B staging map: 512 threads, 2 rows each (k0, k0+1), 4 cols
  const int qk2 = tid >> 4;                // 0..31
  const int k0 = qk2 * 2;
  const int nb = (tid & 15) * 4;
  const int cB2 = qk2 >> 2;                // k0>>3
  const int pr = qk2 & 3;                  // k-pair index in slot
  const float* w2p = w2 + (size_t)e * I_DIM * H_DIM + n0 + nb;

  f32x4 acc[4][2] = {};
  f32x4 fB[2];

  // prologue: DMA A(0) -> buf0, issue B(0)
  {
    unsigned short* dst = &sA2[0][(wv * 32) * 64];
    #pragma unroll
    for (int i = 0; i < 4; ++i) gload_lds16(asrc[i], dst + i * 8 * 64);
  }
  #pragma unroll
  for (int j = 0; j < 2; ++j) LOADF4(fB[j], w2p + (size_t)(k0 + j) * H_DIM);

  char* const sBc = (char*)sB;

  for (int kt = 0; kt < I_DIM / 64; ++kt) {
    WAITV0();                              // fB(kt) + DMA(kt) complete
    #pragma unroll
    for (int j = 0; j < 4; ++j) {
      int n = nb + j;
      unsigned int o16 = (unsigned)((cB2 * 64 + n) << 4) ^ (unsigned)(((n >> 3) & 7) << 4);
      *(unsigned int*)(sBc + o16 + pr * 4) = pack2bf(fB[0][j], fB[1][j]);
    }
    if (kt < I_DIM / 64 - 1) {
      const float* bn = w2p + (size_t)((kt + 1) * 64 + k0) * H_DIM;
      #pragma unroll
      for (int j = 0; j < 2; ++j) LOADF4(fB[j], bn + (size_t)j * H_DIM);
    }
    BAR_LGKM();
    if (kt < I_DIM / 64 - 1) {
      unsigned short* dst = &sA2[(kt + 1) & 1][(wv * 32) * 64];
      #pragma unroll
      for (int i = 0; i < 4; ++i) gload_lds16(asrc[i] + (kt + 1) * 64, dst + i * 8 * 64);
    }
    const char* sAb = (const char*)&sA2[kt & 1][0];
    __builtin_amdgcn_s_setprio(1);
    #pragma unroll
    for (int ks = 0; ks < 2; ++ks) {
      bf16x8 af[4];
      #pragma unroll
      for (int mi = 0; mi < 4; ++mi) {
        int m = wm * 64 + mi * 16 + l15;
        U4B8 t; t.u = *(const uint4*)(sAb + m * 128 + (((ks * 4 + lhi) ^ (m & 7)) << 4));
        af[mi] = t.b;
      }
      #pragma unroll
      for (int ni = 0; ni < 2; ++ni) {
        int n = wn * 32 + ni * 16 + l15;
        int c = ks * 4 + lhi;
        unsigned int o = (unsigned)((c * 64 + n) << 4) ^ (unsigned)(((n >> 3) & 7) << 4);
        U4B8 tb; tb.u = *(const uint4*)(sBc + o);
        #pragma unroll
        for (int mi = 0; mi < 4; ++mi)
          acc[mi][ni] = __builtin_amdgcn_mfma_f32_16x16x32_bf16(af[mi], tb.b, acc[mi][ni], 0, 0, 0);
      }
    }
    __builtin_amdgcn_s_setprio(0);
    BAR_FREE();
  }

  // epilogue: scatter-add to token rows
  #pragma unroll
  for (int mi = 0; mi < 4; ++mi) {
    #pragma unroll
    for (int j = 0; j < 4; ++j) {
      int row = wm * 64 + mi * 16 + lhi * 4 + j;
      if (rt * 256 + row < R) {
        float* ob = out + (size_t)s_tok[row] * H_DIM + n0 + wn * 32;
        #pragma unroll
        for (int ni = 0; ni < 2; ++ni) {
          atomicAdd(ob + ni * 16 + l15, acc[mi][ni][j]);
        }
      }
    }
  }
}

extern "C" void kernel_launch(void* const* d_in, const int* in_sizes, int n_in,
                              void* d_out, int out_size, void* d_ws, size_t ws_size,
                              hipStream_t stream)
{
  const float* hs = (const float*)d_in[0];
  const float* gw = (const float*)d_in[1];
  const float* eb = (const float*)d_in[2];
  const float* w1 = (const float*)d_in[3];
  const float* w3 = (const float*)d_in[4];
  const float* w2 = (const float*)d_in[5];
  float* out = (float*)d_out;

  char* ws = (char*)d_ws;
  int*   tk_id   = (int*)(ws);                          // 49152 B
  float* tk_w    = (float*)(ws + 49152);                // 49152 B
  int*   off     = (int*)(ws + 98304);                  // 512 B (65 used)
  int*   row_tok = (int*)(ws + 98816);                  // 49152 B
  float* row_wt  = (float*)(ws + 147968);               // 49152 B
  unsigned short* xb  = (unsigned short*)(ws + 197120); // 4 MB bf16 hs
  unsigned short* act = (unsigned short*)(ws + 197120 + 4194304); // 12.58 MB

  hipMemsetAsync(out, 0, (size_t)T_TOK * H_DIM * sizeof(float), stream);
  hipLaunchKernelGGL(router_kernel, dim3(T_TOK), dim3(64), 0, stream,
                     hs, gw, eb, tk_id, tk_w, xb);
  hipLaunchKernelGGL(build_rows_kernel, dim3(1), dim3(1024), 0, stream,
                     tk_id, tk_w, off, row_tok, row_wt);
  hipLaunchKernelGGL(gemm1_kernel, dim3(8 * E_NUM, 8, 1), dim3(512), 0, stream,
                     xb, w1, w3, off, row_tok, row_wt, act);
  hipLaunchKernelGGL(gemm2_kernel, dim3(16 * E_NUM, 8, 1), dim3(512), 0, stream,
                     act, w2, off, row_tok, out);
}

// Round 6
// 244.484 us; speedup vs baseline: 1.8450x; 1.0070x over previous
//
#include <hip/hip_runtime.h>
#include <hip/hip_bf16.h>

#define T_TOK 2048
#define H_DIM 1024
#define I_DIM 512
#define E_NUM 64
#define TOPK  6
#define NROWS (T_TOK * TOPK)

typedef __attribute__((ext_vector_type(8))) short bf16x8;
typedef __attribute__((ext_vector_type(4))) float f32x4;

union U4B8 { uint4 u; bf16x8 b; };

__device__ __forceinline__ unsigned int f2bf(float x) {
  unsigned int u = __float_as_uint(x);
  return (u + 0x7fffu + ((u >> 16) & 1u)) >> 16;   // RNE
}
__device__ __forceinline__ unsigned int pack2bf(float lo, float hi) {
  __hip_bfloat162 h = __float22bfloat162_rn(make_float2(lo, hi));
  return *reinterpret_cast<unsigned int*>(&h);     // v_cvt_pk_bf16_f32
}

// volatile asm load: compiler cannot sink it to the use site -> true prefetch
#define LOADF4(dst, p) \
  asm volatile("global_load_dwordx4 %0, %1, off" : "=v"(dst) : "v"(p))

// counted wait: N must be a literal token
#define WAITVN(N) do { asm volatile("s_waitcnt vmcnt(" #N ")" ::: "memory"); \
  __builtin_amdgcn_sched_barrier(0); } while (0)

// producer barrier: drain LDS writes only; vmem loads stay in flight
#define BAR_LGKM() do { __builtin_amdgcn_sched_barrier(0); \
  asm volatile("s_waitcnt lgkmcnt(0)\n\ts_barrier" ::: "memory"); \
  __builtin_amdgcn_sched_barrier(0); } while (0)

// consumer barrier: no waitcnt at all
#define BAR_FREE() do { __builtin_amdgcn_sched_barrier(0); \
  asm volatile("s_barrier" ::: "memory"); \
  __builtin_amdgcn_sched_barrier(0); } while (0)

__device__ __forceinline__ void gload_lds16(const void* gsrc, void* ldst) {
  __builtin_amdgcn_global_load_lds(
      (const __attribute__((address_space(1))) unsigned int*)gsrc,
      (__attribute__((address_space(3))) unsigned int*)ldst, 16, 0, 0);
}

// ---------------- router: logits + sigmoid + grouped top-k + hs->bf16 ------
__global__ __launch_bounds__(64)
void router_kernel(const float* __restrict__ hs, const float* __restrict__ gw,
                   const float* __restrict__ eb, int* __restrict__ tk_id,
                   float* __restrict__ tk_w, unsigned short* __restrict__ xb)
{
  const int t = blockIdx.x;
  const int lane = threadIdx.x;          // lane == expert
  __shared__ float sh[H_DIM];
  const float4* hrow = (const float4*)(hs + (size_t)t * H_DIM);
  float4* sh4 = (float4*)sh;
  for (int i = lane; i < H_DIM / 4; i += 64) sh4[i] = hrow[i];
  __syncthreads();

  // emit bf16 copy of this token's row (consumed by gemm1 A-staging)
  {
    uint4* xrow = (uint4*)(xb + (size_t)t * H_DIM);
    #pragma unroll
    for (int f = 0; f < 2; ++f) {
      int i = lane + f * 64;                    // uint4 index 0..127
      float4 a = sh4[i * 2], b = sh4[i * 2 + 1];
      uint4 o;
      o.x = pack2bf(a.x, a.y); o.y = pack2bf(a.z, a.w);
      o.z = pack2bf(b.x, b.y); o.w = pack2bf(b.z, b.w);
      xrow[i] = o;
    }
  }

  const float* w = gw + (size_t)lane * H_DIM;
  float acc = 0.f;
  for (int k = 0; k < H_DIM; k += 4) {
    float4 wv = *(const float4*)(w + k);
    acc += sh[k] * wv.x + sh[k + 1] * wv.y + sh[k + 2] * wv.z + sh[k + 3] * wv.w;
  }
  const float score = 1.f / (1.f + expf(-acc));
  const float sfc = score + eb[lane];

  float m1v = sfc; int m1i = lane;
  #pragma unroll
  for (int d = 1; d < 8; d <<= 1) {
    float ov = __shfl_xor(m1v, d); int oi = __shfl_xor(m1i, d);
    if (ov > m1v || (ov == m1v && oi < m1i)) { m1v = ov; m1i = oi; }
  }
  float v2 = (lane == m1i) ? -INFINITY : sfc;
  #pragma unroll
  for (int d = 1; d < 8; d <<= 1) v2 = fmaxf(v2, __shfl_xor(v2, d));
  const float gscore = m1v + v2;

  const int myg = lane >> 3;
  int rank = 0;
  #pragma unroll
  for (int g = 0; g < 8; ++g) {
    float gs = __shfl(gscore, g * 8);
    if (gs > gscore || (gs == gscore && g < myg)) rank++;
  }
  float mv = (rank < 4) ? sfc : -INFINITY;

  int isel[TOPK]; float wsel[TOPK]; float wsum = 0.f;
  #pragma unroll
  for (int j = 0; j < TOPK; ++j) {
    float av = mv; int ai = lane;
    #pragma unroll
    for (int d = 1; d < 64; d <<= 1) {
      float ov = __shfl_xor(av, d); int oi = __shfl_xor(ai, d);
      if (ov > av || (ov == av && oi < ai)) { av = ov; ai = oi; }
    }
    float wj = __shfl(score, ai);
    isel[j] = ai; wsel[j] = wj; wsum += wj;
    if (lane == ai) mv = -INFINITY;
  }
  if (lane == 0) {
    float inv = 1.f / wsum;
    #pragma unroll
    for (int j = 0; j < TOPK; ++j) {
      tk_id[t * TOPK + j] = isel[j];
      tk_w[t * TOPK + j] = wsel[j] * inv;
    }
  }
}

// ---------------- counting-sort rows by expert ----------------
__global__ __launch_bounds__(1024)
void build_rows_kernel(const int* __restrict__ tk_id, const float* __restrict__ tk_w,
                       int* __restrict__ off, int* __restrict__ row_tok,
                       float* __restrict__ row_wt)
{
  __shared__ int cnt[E_NUM];
  __shared__ int base[E_NUM];
  const int tid = threadIdx.x;
  if (tid < E_NUM) cnt[tid] = 0;
  __syncthreads();
  for (int i = tid; i < NROWS; i += 1024) atomicAdd(&cnt[tk_id[i]], 1);
  __syncthreads();
  if (tid == 0) {
    int s = 0;
    for (int e = 0; e < E_NUM; ++e) { base[e] = s; off[e] = s; s += cnt[e]; }
    off[E_NUM] = s;
  }
  __syncthreads();
  if (tid < E_NUM) cnt[tid] = base[tid];
  __syncthreads();
  for (int i = tid; i < NROWS; i += 1024) {
    int e = tk_id[i];
    int p = atomicAdd(&cnt[e], 1);
    row_tok[p] = i / TOPK;
    row_wt[p] = tk_w[i];
  }
}

// ---------------- gemm1: act = silu(X@w1) * (X@w3) * wt  (bf16 out) --------
// BM=256 BN=64 BK=64, 512 threads / 8 waves (wave = 64 rows x 32 cols).
// R5-proven structure (A dbuf global_load_lds, flattened grid). Single delta:
// counted vmcnt instead of drain-to-0.  Per-wave queue (issue order):
//   entry iter kt: [B(kt):4, A(kt):4]
//   top wait vmcnt(4)            -> B(kt) retired, A(kt) in flight
//   write B(kt); issue B(kt+1)   -> [A(kt):4, B(kt+1):4]
//   pre-barrier vmcnt(4) (last:0)-> A(kt) retired; barrier publishes LDS
//   BAR_LGKM; DMA A(kt+1)        -> [B(kt+1):4, A(kt+1):4] ride across MFMA
// LDS = 64K(A dbuf) + 8K + 8K = 80KB -> 2 blocks/CU.
__global__ __launch_bounds__(512, 4)
void gemm1_kernel(const unsigned short* __restrict__ xb, const float* __restrict__ w1,
                  const float* __restrict__ w3, const int* __restrict__ off,
                  const int* __restrict__ row_tok, const float* __restrict__ row_wt,
                  unsigned short* __restrict__ act)
{
  const int e = blockIdx.x & 63;
  const int n0 = (blockIdx.x >> 6) * 64;
  const int r0 = off[e];
  const int R = off[e + 1] - r0;
  const int rt = blockIdx.y;
  if (rt * 256 >= R) return;

  __shared__ unsigned short sA2[2][256 * 64];  // 64KB dbuf, per-row chunk swizzle
  __shared__ unsigned int sB1[8 * 64 * 4];     // 8KB [c=k>>3][n] 16B slots, swizzled
  __shared__ unsigned int sB3[8 * 64 * 4];     // 8KB

  const int tid = threadIdx.x;
  const int lane = tid & 63;
  const int wv = tid >> 6;                 // 0..7
  const int wm = wv >> 1, wn = wv & 1;     // wave tile: rows wm*64, cols wn*32
  const int l15 = lane & 15, lhi = lane >> 4;

  // A DMA map: wave fills rows wv*32..wv*32+31, 4 DMAs of 8 rows each.
  // LDS linear; source chunk pre-swizzled: slot s of row ar holds chunk s^(ar&7).
  const unsigned short* asrc[4];
  #pragma unroll
  for (int i = 0; i < 4; ++i) {
    int ar = wv * 32 + i * 8 + (lane >> 3);
    int g = rt * 256 + ar; if (g >= R) g = R - 1;
    int tok = row_tok[r0 + g];
    asrc[i] = xb + (size_t)tok * H_DIM + (((lane & 7) ^ (ar & 7)) << 3);
  }

  // B staging: tid<256 -> w1, tid>=256 -> w3 (wave-uniform split)
  const int ht = tid & 255;
  const int qk = ht >> 4;                  // 0..15
  const int qn = ht & 15;
  const int k0 = qk * 4;
  const int nb = qn * 4;
  const int cB = qk >> 1;
  const int bOff = (k0 & 4) * 2;           // byte offset {0,8} inside 16B slot
  const float* wp = ((tid < 256) ? w1 : w3) + (size_t)e * H_DIM * I_DIM + n0 + nb;
  char* const sBw = (char*)((tid < 256) ? sB1 : sB3);

  f32x4 acc1[4][2] = {};
  f32x4 acc3[4][2] = {};
  f32x4 fB[4];

  // prologue: issue B(0) FIRST, then DMA A(0) -> queue [B0:4, A0:4]
  #pragma unroll
  for (int j = 0; j < 4; ++j) LOADF4(fB[j], wp + (size_t)(k0 + j) * I_DIM);
  {
    unsigned short* dst = &sA2[0][(wv * 32) * 64];
    #pragma unroll
    for (int i = 0; i < 4; ++i) gload_lds16(asrc[i], dst + i * 8 * 64);
  }

  char* const sB1c = (char*)sB1;
  char* const sB3c = (char*)sB3;

  for (int kt = 0; kt < H_DIM / 64; ++kt) {
    WAITVN(4);                             // B(kt) retired; A(kt) in flight
    // pack + write B tile (each thread: one matrix)
    #pragma unroll
    for (int j = 0; j < 4; ++j) {
      int n = nb + j;
      unsigned int o16 = (unsigned)((cB * 64 + n) << 4) ^ (unsigned)(((n >> 3) & 7) << 4);
      uint2 p = make_uint2(pack2bf(fB[0][j], fB[1][j]), pack2bf(fB[2][j], fB[3][j]));
      *(uint2*)(sBw + o16 + bOff) = p;
    }
    // issue B(kt+1): register dest, stays in flight across MFMA + barriers
    if (kt < H_DIM / 64 - 1) {
      const float* bn = wp + (size_t)((kt + 1) * 64 + k0) * I_DIM;
      #pragma unroll
      for (int j = 0; j < 4; ++j) LOADF4(fB[j], bn + (size_t)j * I_DIM);
    }
    // retire A(kt) (this wave's own DMAs); barrier publishes across waves
    if (kt < H_DIM / 64 - 1) { WAITVN(4); } else { WAITVN(0); }
    BAR_LGKM();
    // DMA A(kt+1) into other buffer (all waves past MFMA(kt-1) reads)
    if (kt < H_DIM / 64 - 1) {
      unsigned short* dst = &sA2[(kt + 1) & 1][(wv * 32) * 64];
      #pragma unroll
      for (int i = 0; i < 4; ++i) gload_lds16(asrc[i] + (kt + 1) * 64, dst + i * 8 * 64);
    }
    // MFMA on buf[kt&1] + sB1/sB3
    const char* sAb = (const char*)&sA2[kt & 1][0];
    __builtin_amdgcn_s_setprio(1);
    #pragma unroll
    for (int ks = 0; ks < 2; ++ks) {
      bf16x8 af[4];
      #pragma unroll
      for (int mi = 0; mi < 4; ++mi) {
        int m = wm * 64 + mi * 16 + l15;
        U4B8 t; t.u = *(const uint4*)(sAb + m * 128 + (((ks * 4 + lhi) ^ (m & 7)) << 4));
        af[mi] = t.b;
      }
      #pragma unroll
      for (int ni = 0; ni < 2; ++ni) {
        int n = wn * 32 + ni * 16 + l15;
        int c = ks * 4 + lhi;
        unsigned int o = (unsigned)((c * 64 + n) << 4) ^ (unsigned)(((n >> 3) & 7) << 4);
        U4B8 t1; t1.u = *(const uint4*)(sB1c + o);
        U4B8 t3; t3.u = *(const uint4*)(sB3c + o);
        #pragma unroll
        for (int mi = 0; mi < 4; ++mi) {
          acc1[mi][ni] = __builtin_amdgcn_mfma_f32_16x16x32_bf16(af[mi], t1.b, acc1[mi][ni], 0, 0, 0);
          acc3[mi][ni] = __builtin_amdgcn_mfma_f32_16x16x32_bf16(af[mi], t3.b, acc3[mi][ni], 0, 0, 0);
        }
      }
    }
    __builtin_amdgcn_s_setprio(0);
    BAR_FREE();
  }

  // epilogue: act = silu(g) * u * wt (bf16)
  #pragma unroll
  for (int mi = 0; mi < 4; ++mi) {
    #pragma unroll
    for (int j = 0; j < 4; ++j) {
      int row = wm * 64 + mi * 16 + lhi * 4 + j;
      int rg = rt * 256 + row;
      if (rg < R) {
        float wt = row_wt[r0 + rg];
        size_t rbase = (size_t)(r0 + rg) * I_DIM + n0 + wn * 32;
        #pragma unroll
        for (int ni = 0; ni < 2; ++ni) {
          float g = acc1[mi][ni][j];
          float u = acc3[mi][ni][j];
          float a = g / (1.f + __expf(-g)) * u * wt;
          act[rbase + ni * 16 + l15] = (unsigned short)f2bf(a);
        }
      }
    }
  }
}

// ---------------- gemm2: out[tok] += act @ w2 ----------------
// BM=256 BN=64 BK=64, 512 threads / 8 waves; w2 streams once per expert.
// R5-proven structure; counted vmcnt delta (B=2 ops: top 4, pre-barrier 2/0).
// LDS = 64K + 8K + 1K -> 2 blocks/CU.
__global__ __launch_bounds__(512, 4)
void gemm2_kernel(const unsigned short* __restrict__ act, const float* __restrict__ w2,
                  const int* __restrict__ off, const int* __restrict__ row_tok,
                  float* __restrict__ out)
{
  const int e = blockIdx.x & 63;
  const int n0 = (blockIdx.x >> 6) * 64;
  const int r0 = off[e];
  const int R = off[e + 1] - r0;
  const int rt = blockIdx.y;
  if (rt * 256 >= R) return;

  __shared__ unsigned short sA2[2][256 * 64];  // 64KB dbuf
  __shared__ unsigned int sB[8 * 64 * 4];      // 8KB, swizzled
  __shared__ int s_tok[256];

  const int tid = threadIdx.x;
  if (tid < 256) {
    int r = rt * 256 + tid;
    int rr = (r < R) ? r : (R - 1);
    s_tok[tid] = row_tok[r0 + rr];
  }
  __syncthreads();

  const int lane = tid & 63;
  const int wv = tid >> 6;
  const int wm = wv >> 1, wn = wv & 1;
  const int l15 = lane & 15, lhi = lane >> 4;

  // A DMA map: wave fills rows wv*32..+31, 4 DMAs of 8 rows
  const unsigned short* asrc[4];
  #pragma unroll
  for (int i = 0; i < 4; ++i) {
    int ar = wv * 32 + i * 8 + (lane >> 3);
    int g = rt * 256 + ar; if (g >= R) g = R - 1;
    asrc[i] = act + (size_t)(r0 + g) * I_DIM + (((lane & 7) ^ (ar & 7)) << 3);
  }

  // B staging map: 512 threads, 2 rows each (k0, k0+1), 4 cols
  const int qk2 = tid >> 4;                // 0..31
  const int k0 = qk2 * 2;
  const int nb = (tid & 15) * 4;
  const int cB2 = qk2 >> 2;                // k0>>3
  const int pr = qk2 & 3;                  // k-pair index in slot
  const float* w2p = w2 + (size_t)e * I_DIM * H_DIM + n0 + nb;

  f32x4 acc[4][2] = {};
  f32x4 fB[2];

  // prologue: issue B(0) FIRST, then DMA A(0) -> queue [B0:2, A0:4]
  #pragma unroll
  for (int j = 0; j < 2; ++j) LOADF4(fB[j], w2p + (size_t)(k0 + j) * H_DIM);
  {
    unsigned short* dst = &sA2[0][(wv * 32) * 64];
    #pragma unroll
    for (int i = 0; i < 4; ++i) gload_lds16(asrc[i], dst + i * 8 * 64);
  }

  char* const sBc = (char*)sB;

  for (int kt = 0; kt < I_DIM / 64; ++kt) {
    WAITVN(4);                             // B(kt) retired; A(kt) in flight
    #pragma unroll
    for (int j = 0; j < 4; ++j) {
      int n = nb + j;
      unsigned int o16 = (unsigned)((cB2 * 64 + n) << 4) ^ (unsigned)(((n >> 3) & 7) << 4);
      *(unsigned int*)(sBc + o16 + pr * 4) = pack2bf(fB[0][j], fB[1][j]);
    }
    if (kt < I_DIM / 64 - 1) {
      const float* bn = w2p + (size_t)((kt + 1) * 64 + k0) * H_DIM;
      #pragma unroll
      for (int j = 0; j < 2; ++j) LOADF4(fB[j], bn + (size_t)j * H_DIM);
    }
    // retire A(kt); B(kt+1) stays in flight
    if (kt < I_DIM / 64 - 1) { WAITVN(2); } else { WAITVN(0); }
    BAR_LGKM();
    if (kt < I_DIM / 64 - 1) {
      unsigned short* dst = &sA2[(kt + 1) & 1][(wv * 32) * 64];
      #pragma unroll
      for (int i = 0; i < 4; ++i) gload_lds16(asrc[i] + (kt + 1) * 64, dst + i * 8 * 64);
    }
    const char* sAb = (const char*)&sA2[kt & 1][0];
    __builtin_amdgcn_s_setprio(1);
    #pragma unroll
    for (int ks = 0; ks < 2; ++ks) {
      bf16x8 af[4];
      #pragma unroll
      for (int mi = 0; mi < 4; ++mi) {
        int m = wm * 64 + mi * 16 + l15;
        U4B8 t; t.u = *(const uint4*)(sAb + m * 128 + (((ks * 4 + lhi) ^ (m & 7)) << 4));
        af[mi] = t.b;
      }
      #pragma unroll
      for (int ni = 0; ni < 2; ++ni) {
        int n = wn * 32 + ni * 16 + l15;
        int c = ks * 4 + lhi;
        unsigned int o = (unsigned)((c * 64 + n) << 4) ^ (unsigned)(((n >> 3) & 7) << 4);
        U4B8 tb; tb.u = *(const uint4*)(sBc + o);
        #pragma unroll
        for (int mi = 0; mi < 4; ++mi)
          acc[mi][ni] = __builtin_amdgcn_mfma_f32_16x16x32_bf16(af[mi], tb.b, acc[mi][ni], 0, 0, 0);
      }
    }
    __builtin_amdgcn_s_setprio(0);
    BAR_FREE();
  }

  // epilogue: scatter-add to token rows
  #pragma unroll
  for (int mi = 0; mi < 4; ++mi) {
    #pragma unroll
    for (int j = 0; j < 4; ++j) {
      int row = wm * 64 + mi * 16 + lhi * 4 + j;
      if (rt * 256 + row < R) {
        float* ob = out + (size_t)s_tok[row] * H_DIM + n0 + wn * 32;
        #pragma unroll
        for (int ni = 0; ni < 2; ++ni) {
          atomicAdd(ob + ni * 16 + l15, acc[mi][ni][j]);
        }
      }
    }
  }
}

extern "C" void kernel_launch(void* const* d_in, const int* in_sizes, int n_in,
                              void* d_out, int out_size, void* d_ws, size_t ws_size,
                              hipStream_t stream)
{
  const float* hs = (const float*)d_in[0];
  const float* gw = (const float*)d_in[1];
  const float* eb = (const float*)d_in[2];
  const float* w1 = (const float*)d_in[3];
  const float* w3 = (const float*)d_in[4];
  const float* w2 = (const float*)d_in[5];
  float* out = (float*)d_out;

  char* ws = (char*)d_ws;
  int*   tk_id   = (int*)(ws);                          // 49152 B
  float* tk_w    = (float*)(ws + 49152);                // 49152 B
  int*   off     = (int*)(ws + 98304);                  // 512 B (65 used)
  int*   row_tok = (int*)(ws + 98816);                  // 49152 B
  float* row_wt  = (float*)(ws + 147968);               // 49152 B
  unsigned short* xb  = (unsigned short*)(ws + 197120); // 4 MB bf16 hs
  unsigned short* act = (unsigned short*)(ws + 197120 + 4194304); // 12.58 MB

  hipMemsetAsync(out, 0, (size_t)T_TOK * H_DIM * sizeof(float), stream);
  hipLaunchKernelGGL(router_kernel, dim3(T_TOK), dim3(64), 0, stream,
                     hs, gw, eb, tk_id, tk_w, xb);
  hipLaunchKernelGGL(build_rows_kernel, dim3(1), dim3(1024), 0, stream,
                     tk_id, tk_w, off, row_tok, row_wt);
  hipLaunchKernelGGL(gemm1_kernel, dim3(8 * E_NUM, 8, 1), dim3(512), 0, stream,
                     xb, w1, w3, off, row_tok, row_wt, act);
  hipLaunchKernelGGL(gemm2_kernel, dim3(16 * E_NUM, 8, 1), dim3(512), 0, stream,
                     act, w2, off, row_tok, out);
}